// Round 12
// baseline (325.751 us; speedup 1.0000x reference)
//
#include <hip/hip_runtime.h>

#define BATCH 8
#define C_DIM 768
#define HW 2304
#define N_TOK 18432   // BATCH*HW
#define E_NUM 8
#define HID 1536

#define BM 128
#define NT_A (HID / 64)          // 24 n-tiles (BN=64, two B matrices)
#define NT_B (C_DIM / 128)       // 6 n-tiles  (BN=128)
#define NKA (C_DIM / 32)         // 24 K-steps pass A (div by 3)
#define NKB (HID / 32)           // 48 K-steps pass B (div by 3)
#define MAXROWS (N_TOK + 1024)   // padded routed-row capacity (152 panels)

#define GT 64                    // gate: tokens per block
#define KSL 256                  // gate: K-slice per block
#define NSL (C_DIM / KSL)        // 3 slices

typedef short s16x8 __attribute__((ext_vector_type(8)));
typedef unsigned short u16x8 __attribute__((ext_vector_type(8)));
typedef float f32x4 __attribute__((ext_vector_type(4)));

__device__ __forceinline__ unsigned short f2bf(float f) {
  unsigned int u = __float_as_uint(f);
  u = u + 0x7fffu + ((u >> 16) & 1u);
  return (unsigned short)(u >> 16);
}

// async global -> LDS, 16B per lane; LDS dest = wave-uniform base + lane*16
__device__ __forceinline__ void gll16(const unsigned short* g, unsigned short* l) {
  __builtin_amdgcn_global_load_lds(
      (const __attribute__((address_space(1))) unsigned int*)g,
      (__attribute__((address_space(3))) unsigned int*)l, 16, 0, 0);
}

// fused weight prep: all three weights -> packed bf16 panels
// [e][n-panel][k-step][PROWS x 32k, 16B-chunk XOR by row]
__global__ __launch_bounds__(256) void k_prep_all(
    const float* __restrict__ w1, const float* __restrict__ w3,
    const float* __restrict__ w2, unsigned short* __restrict__ w1t,
    unsigned short* __restrict__ w3t, unsigned short* __restrict__ w2t) {
  __shared__ float tile[32][33];
  int gid = blockIdx.x;
  const float* in;
  unsigned short* outT;
  int S, NK, PSH, bx, by, e;
  if (gid < 9216) {                 // w1: grid (48,24,8), PSH=6 (64-col panels)
    in = w1; outT = w1t; S = HID; NK = NKA; PSH = 6;
    bx = gid % 48; by = (gid / 48) % 24; e = gid / (48 * 24);
  } else if (gid < 18432) {         // w3
    gid -= 9216;
    in = w3; outT = w3t; S = HID; NK = NKA; PSH = 6;
    bx = gid % 48; by = (gid / 48) % 24; e = gid / (48 * 24);
  } else {                          // w2: grid (24,48,8), PSH=7 (128-col panels)
    gid -= 18432;
    in = w2; outT = w2t; S = C_DIM; NK = NKB; PSH = 7;
    bx = gid % 24; by = (gid / 24) % 48; e = gid / (24 * 48);
  }
  const int s0 = bx * 32, r0 = by * 32;
  const int tx = threadIdx.x, ty = threadIdx.y;
  const size_t esz = (size_t)C_DIM * HID;
  const float* ip = in + (size_t)e * esz;
  unsigned short* op = outT + (size_t)e * esz;
#pragma unroll
  for (int i = 0; i < 4; i++) {
    tile[ty + i * 8][tx] = ip[(size_t)(r0 + ty + i * 8) * S + s0 + tx];
  }
  __syncthreads();
  const int t = r0 >> 5;
  const int q = tx >> 3;
#pragma unroll
  for (int i = 0; i < 4; i++) {
    const int s = s0 + ty + i * 8;
    const int nloc = s & ((1 << PSH) - 1);
    const int pn = s >> PSH;
    const int slot = q ^ ((nloc >> 1) & 3);
    op[(size_t)(pn * NK + t) * (32 << PSH) + nloc * 32 + (slot << 3) + (tx & 7)] =
        f2bf(tile[tx][ty + i * 8]);
  }
}

// gate stage 1: block = (64 tokens) x (K-slice of 256); 4 waves x 4 outputs.
__global__ __launch_bounds__(256) void k_gate1(const float* __restrict__ x,
                                               const float* __restrict__ wg,
                                               const float* __restrict__ wn,
                                               float* __restrict__ partials,
                                               unsigned short* __restrict__ Xbf) {
  __shared__ float Ws[KSL * 16];
  __shared__ float Xs[GT][65];
  const int tid = threadIdx.x;
  const int lane = tid & 63;
  const int og = tid >> 6;
  const int g = blockIdx.x / NSL;
  const int s = blockIdx.x - g * NSL;
  const int n0 = g * GT;
  const int b = n0 / HW;
  const int hw0 = n0 % HW;
  const int k0 = s * KSL;
  const float* xb = x + ((size_t)b * C_DIM + k0) * HW + hw0;

  for (int idx = tid; idx < KSL * 8; idx += 256) {
    const int r = idx >> 3, c = idx & 7;
    Ws[r * 16 + c] = wg[(k0 + r) * 8 + c];
    Ws[r * 16 + 8 + c] = wn[(k0 + r) * 8 + c];
  }

  const int cl = tid >> 2, q = tid & 3;
  const int xr = tid >> 2, xc = (tid & 3) << 4;
  float acc[4] = {};
  float4 xv[4];
#pragma unroll
  for (int i = 0; i < 4; i++)
    xv[i] = *(const float4*)(xb + (size_t)cl * HW + q * 16 + i * 4);

  for (int kc = 0; kc < KSL; kc += GT) {
    __syncthreads();
#pragma unroll
    for (int i = 0; i < 4; i++) {
      const int col = q * 16 + i * 4;
      Xs[cl][col + 0] = xv[i].x;
      Xs[cl][col + 1] = xv[i].y;
      Xs[cl][col + 2] = xv[i].z;
      Xs[cl][col + 3] = xv[i].w;
    }
    __syncthreads();
    if (kc + GT < KSL) {
#pragma unroll
      for (int i = 0; i < 4; i++)
        xv[i] = *(const float4*)(xb + (size_t)(kc + GT + cl) * HW + q * 16 + i * 4);
    }
    {
      u16x8 pa, pb;
#pragma unroll
      for (int j = 0; j < 8; j++) pa[j] = f2bf(Xs[xc + j][xr]);
#pragma unroll
      for (int j = 0; j < 8; j++) pb[j] = f2bf(Xs[xc + 8 + j][xr]);
      *(u16x8*)&Xbf[(size_t)(n0 + xr) * C_DIM + k0 + kc + xc] = pa;
      *(u16x8*)&Xbf[(size_t)(n0 + xr) * C_DIM + k0 + kc + xc + 8] = pb;
    }
#pragma unroll 16
    for (int k = 0; k < GT; k++) {
      const float xk = Xs[k][lane];
      const float4 wv = *(const float4*)&Ws[(kc + k) * 16 + og * 4];
      acc[0] = fmaf(xk, wv.x, acc[0]);
      acc[1] = fmaf(xk, wv.y, acc[1]);
      acc[2] = fmaf(xk, wv.z, acc[2]);
      acc[3] = fmaf(xk, wv.w, acc[3]);
    }
  }
#pragma unroll
  for (int j = 0; j < 4; j++)
    partials[((size_t)s * 16 + og * 4 + j) * N_TOK + n0 + lane] = acc[j];
}

// gate stage 2: 1 thread per token; fixed-order slice sum -> exact epilogue
__global__ __launch_bounds__(256) void k_gate2(const float* __restrict__ partials,
                                               const float* __restrict__ bg,
                                               const float* __restrict__ bn,
                                               const float* __restrict__ noise,
                                               int* __restrict__ counts,
                                               int* __restrict__ tok_list,
                                               int* __restrict__ pairE,
                                               int* __restrict__ pairPos,
                                               float* __restrict__ pairW) {
  const int n = blockIdx.x * 256 + threadIdx.x;
  if (n >= N_TOK) return;
  float v[16];
#pragma unroll
  for (int e = 0; e < 16; e++) {
    const float p0 = partials[(size_t)(0 * 16 + e) * N_TOK + n];
    const float p1 = partials[(size_t)(1 * 16 + e) * N_TOK + n];
    const float p2 = partials[(size_t)(2 * 16 + e) * N_TOK + n];
    v[e] = (p0 + p1) + p2;
  }
  const float4 nz0 = *(const float4*)(noise + (size_t)n * 8);
  const float4 nz1 = *(const float4*)(noise + (size_t)n * 8 + 4);
  const float nzv[8] = {nz0.x, nz0.y, nz0.z, nz0.w, nz1.x, nz1.y, nz1.z, nz1.w};
  float noisy[E_NUM];
#pragma unroll
  for (int e = 0; e < E_NUM; e++) {
    const float lg = v[e] + bg[e];
    const float nl = v[8 + e] + bn[e];
    const float sp = (nl > 20.f) ? nl : log1pf(expf(nl));
    noisy[e] = lg + nzv[e] * sp;
  }
  int i0 = 0;
#pragma unroll
  for (int e = 1; e < E_NUM; e++) if (noisy[e] > noisy[i0]) i0 = e;
  int i1 = (i0 == 0) ? 1 : 0;
#pragma unroll
  for (int e = 0; e < E_NUM; e++) if (e != i0 && noisy[e] > noisy[i1]) i1 = e;
  const float v0 = noisy[i0], v1 = noisy[i1];
  const float e1 = expf(v1 - v0);
  const float z = 1.f + e1;
  const float p0 = (i0 == 0) ? (1.f / z) : ((i1 == 0) ? (e1 / z) : 0.f);
  const float p1 = (i0 == 1) ? (1.f / z) : ((i1 == 1) ? (e1 / z) : 0.f);
  if (p0 != 0.f) {
    const int pos = atomicAdd(&counts[i0], 1);
    tok_list[i0 * N_TOK + pos] = n;
    pairE[2 * n] = i0; pairPos[2 * n] = pos; pairW[2 * n] = p0;
  } else {
    pairE[2 * n] = -1;
  }
  if (p1 != 0.f) {
    const int pos = atomicAdd(&counts[i1], 1);
    tok_list[i1 * N_TOK + pos] = n;
    pairE[2 * n + 1] = i1; pairPos[2 * n + 1] = pos; pairW[2 * n + 1] = p1;
  } else {
    pairE[2 * n + 1] = -1;
  }
}

// scan: 128-aligned per-expert offsets + active-tile prefix tables
__global__ void k_scan(int* __restrict__ counts, int* __restrict__ offsets,
                       int* __restrict__ tmap) {
  if (threadIdx.x == 0) {
    int s = 0, ta = 0, tb = 0;
    for (int e = 0; e < E_NUM; e++) {
      offsets[e] = s;
      int c = counts[e];
      if (c > N_TOK - s) c = (N_TOK - s > 0) ? (N_TOK - s) : 0;
      counts[e] = c;
      tmap[e] = ta; tmap[16 + e] = tb;
      const int mt = (c + BM - 1) / BM;
      s += mt * BM;
      ta += mt * NT_A;
      tb += mt * NT_B;
    }
    offsets[E_NUM] = s;
    tmap[8] = ta; tmap[24] = tb;
  }
}

// gather routed rows into packed A-panels: [panel][k-step][128 x 32k, chunk-XOR]
__global__ __launch_bounds__(256) void k_compact(const unsigned short* __restrict__ Xbf,
                                                 const int* __restrict__ offsets,
                                                 const int* __restrict__ counts,
                                                 const int* __restrict__ tok_list,
                                                 unsigned short* __restrict__ Xg) {
  const int total = offsets[E_NUM];
  const int half = threadIdx.x >> 7;
  const int lane = threadIdx.x & 127;
  for (int r = blockIdx.x * 2 + half; r < total; r += gridDim.x * 2) {
    int e = 0;
#pragma unroll
    for (int i = 1; i < E_NUM; i++) if (r >= offsets[i]) e = i;
    int pos = r - offsets[e];
    if (pos >= counts[e]) pos = counts[e] - 1;
    const int tok = tok_list[e * N_TOK + pos];
    if (lane < 96) {
      const int t = lane >> 2, q = lane & 3;
      const uint4 v = ((const uint4*)(Xbf + (size_t)tok * C_DIM))[lane];
      const int r7 = r & 127;
      const int slot = q ^ ((r7 >> 1) & 3);
      *(uint4*)(Xg + (size_t)((r >> 7) * NKA + t) * 4096 + r7 * 32 + (slot << 3)) = v;
    }
  }
}

// pass A: H = silu(Xg@w1+b1) * (Xg@w3+b3); packed panels, persistent,
// 3-buffer counted-vmcnt pipeline continuous across tiles; H written packed.
// Tile assignment: atomic work-queue (output-deterministic; order irrelevant).
__global__ __launch_bounds__(256, 3) void k_ffn_a(
    const unsigned short* __restrict__ Xg, const unsigned short* __restrict__ w1t,
    const float* __restrict__ b1, const unsigned short* __restrict__ w3t,
    const float* __restrict__ b3, const int* __restrict__ offsets,
    const int* __restrict__ tmap, int* __restrict__ q,
    unsigned short* __restrict__ H) {
  __shared__ __align__(16) unsigned short As[3][BM * 32];   // 24 KB
  __shared__ __align__(16) unsigned short B1s[3][64 * 32];  // 12 KB
  __shared__ __align__(16) unsigned short B3s[3][64 * 32];  // 12 KB
  __shared__ int vt_s;
  const int tid = threadIdx.x;
  const int lane = tid & 63;
  const int w = tid >> 6;
  const int wm = w >> 1, wn = w & 1;
  const int lrow = lane & 15, lgrp = lane >> 4;
  const int fswz = (lgrp ^ ((lrow >> 1) & 3)) << 3;
  const int wbase = w << 9;
  const int l8 = tid << 3;   // per-lane 16B offset (shorts)
  const int total = tmap[8];

  if (tid == 0) vt_s = atomicAdd(q, 1);
  __syncthreads();
  int vt = vt_s;
  if (vt >= total) return;

#define ADDR_A(VT_, E_, HB_, N0_, AP_, P1_, P3_)                              \
  {                                                                           \
    E_ = 0;                                                                   \
    _Pragma("unroll") for (int i_ = 1; i_ < E_NUM; i_++)                      \
        if ((VT_) >= tmap[i_]) E_ = i_;                                       \
    const int local_ = (VT_) - tmap[E_];                                      \
    const int tm_ = local_ / NT_A;                                            \
    N0_ = (local_ - tm_ * NT_A) * 64;                                         \
    HB_ = offsets[E_] + tm_ * BM;                                             \
    AP_ = Xg + (size_t)(HB_ >> 7) * (NKA * 4096) + l8;                        \
    P1_ = w1t + (size_t)E_ * (C_DIM * HID) + (size_t)((N0_ >> 6) * NKA) * 2048 + l8; \
    P3_ = w3t + (size_t)E_ * (C_DIM * HID) + (size_t)((N0_ >> 6) * NKA) * 2048 + l8; \
  }

#define STAGE_A(AP_, P1_, P3_, TS_, SB_)                                      \
  {                                                                           \
    gll16(AP_ + (TS_) * 4096,        &As[SB_][wbase]);                        \
    gll16(AP_ + (TS_) * 4096 + 2048, &As[SB_][2048 + wbase]);                 \
    gll16(P1_ + (TS_) * 2048, &B1s[SB_][wbase]);                              \
    gll16(P3_ + (TS_) * 2048, &B3s[SB_][wbase]);                              \
  }

#define STEP_A(T_, RB_, SB_)                                                  \
  {                                                                           \
    if (has_next || (T_) < NKA - 1)                                           \
      asm volatile("s_waitcnt vmcnt(4)" ::: "memory");                        \
    else                                                                      \
      asm volatile("s_waitcnt vmcnt(0)" ::: "memory");                        \
    __builtin_amdgcn_s_barrier();                                             \
    asm volatile("" ::: "memory");                                            \
    const int ts_ = (T_) + 2;                                                 \
    if (ts_ < NKA) {                                                          \
      STAGE_A(aP, p1P, p3P, ts_, SB_);                                        \
    } else if (has_next) {                                                    \
      STAGE_A(naP, np1P, np3P, ts_ - NKA, SB_);                               \
    }                                                                         \
    s16x8 af[4], bf1[2], bf3[2];                                              \
    _Pragma("unroll") for (int mf = 0; mf < 4; mf++)                          \
        af[mf] = *(const s16x8*)&As[RB_][(wm * 64 + mf * 16 + lrow) * 32 + fswz]; \
    _Pragma("unroll") for (int nf = 0; nf < 2; nf++) {                        \
      bf1[nf] = *(const s16x8*)&B1s[RB_][(wn * 32 + nf * 16 + lrow) * 32 + fswz]; \
      bf3[nf] = *(const s16x8*)&B3s[RB_][(wn * 32 + nf * 16 + lrow) * 32 + fswz]; \
    }                                                                         \
    __builtin_amdgcn_s_setprio(1);                                            \
    _Pragma("unroll") for (int mf = 0; mf < 4; mf++)                          \
      _Pragma("unroll") for (int nf = 0; nf < 2; nf++) {                      \
        acc1[mf][nf] = __builtin_amdgcn_mfma_f32_16x16x32_bf16(af[mf], bf1[nf], acc1[mf][nf], 0, 0, 0); \
        acc3[mf][nf] = __builtin_amdgcn_mfma_f32_16x16x32_bf16(af[mf], bf3[nf], acc3[mf][nf], 0, 0, 0); \
      }                                                                       \
    __builtin_amdgcn_s_setprio(0);                                            \
  }

  int e, hb, n0;
  const unsigned short *aP, *p1P, *p3P;
  ADDR_A(vt, e, hb, n0, aP, p1P, p3P);
  STAGE_A(aP, p1P, p3P, 0, 0);
  STAGE_A(aP, p1P, p3P, 1, 1);

  while (true) {
    if (tid == 0) vt_s = atomicAdd(q, 1);
    __syncthreads();
    const int vt_next = vt_s;
    const bool has_next = vt_next < total;
    int ne = 0, nhb = 0, nn0 = 0;
    const unsigned short *naP = nullptr, *np1P = nullptr, *np3P = nullptr;
    if (has_next) ADDR_A(vt_next, ne, nhb, nn0, naP, np1P, np3P);
    f32x4 acc1[4][2] = {};
    f32x4 acc3[4][2] = {};
    for (int tt = 0; tt < NKA; tt += 3) {
      STEP_A(tt + 0, 0, 2);
      STEP_A(tt + 1, 1, 0);
      STEP_A(tt + 2, 2, 1);
    }
    const int Ph = hb >> 7;
#pragma unroll
    for (int mf = 0; mf < 4; mf++)
#pragma unroll
      for (int nf = 0; nf < 2; nf++) {
        const int col = n0 + wn * 32 + nf * 16 + lrow;
        const float bb1 = b1[e * HID + col];
        const float bb3 = b3[e * HID + col];
        const int th = col >> 5;
        const int kq = (col & 31) >> 3;
        const int ko = col & 7;
        unsigned short* hp = H + (size_t)(Ph * NKB + th) * 4096 + ko;
#pragma unroll
        for (int r = 0; r < 4; r++) {
          const int gr = wm * 64 + mf * 16 + lgrp * 4 + r;
          const float g1 = acc1[mf][nf][r] + bb1;
          const float g3 = acc3[mf][nf][r] + bb3;
          const float hv = g1 / (1.f + expf(-g1)) * g3;
          hp[gr * 32 + ((kq ^ ((gr >> 1) & 3)) << 3)] = f2bf(hv);
        }
      }
    if (!has_next) break;
    vt = vt_next;
    e = ne; hb = nhb; n0 = nn0;
    aP = naP; p1P = np1P; p3P = np3P;
  }
#undef STEP_A
#undef STAGE_A
#undef ADDR_A
}

// pass B: Out = H @ w2 + b2; BM=128 x BN=128, packed panels, same pipeline + queue
__global__ __launch_bounds__(256, 3) void k_ffn_b(
    const unsigned short* __restrict__ H, const unsigned short* __restrict__ w2t,
    const float* __restrict__ b2, const int* __restrict__ offsets,
    const int* __restrict__ tmap, int* __restrict__ q, float* __restrict__ Out) {
  __shared__ __align__(16) unsigned short As[3][BM * 32];   // 24 KB
  __shared__ __align__(16) unsigned short Bs[3][128 * 32];  // 24 KB
  __shared__ int vt_s;
  const int tid = threadIdx.x;
  const int lane = tid & 63;
  const int w = tid >> 6;
  const int wm = w >> 1, wn = w & 1;
  const int lrow = lane & 15, lgrp = lane >> 4;
  const int fswz = (lgrp ^ ((lrow >> 1) & 3)) << 3;
  const int wbase = w << 9;
  const int l8 = tid << 3;
  const int total = tmap[24];

  if (tid == 0) vt_s = atomicAdd(q, 1);
  __syncthreads();
  int vt = vt_s;
  if (vt >= total) return;

#define ADDR_B(VT_, E_, HB_, N0_, AP_, BP_)                                   \
  {                                                                           \
    E_ = 0;                                                                   \
    _Pragma("unroll") for (int i_ = 1; i_ < E_NUM; i_++)                      \
        if ((VT_) >= tmap[16 + i_]) E_ = i_;                                  \
    const int local_ = (VT_) - tmap[16 + E_];                                 \
    const int tm_ = local_ / NT_B;                                            \
    N0_ = (local_ - tm_ * NT_B) * 128;                                        \
    HB_ = offsets[E_] + tm_ * BM;                                             \
    AP_ = H + (size_t)(HB_ >> 7) * (NKB * 4096) + l8;                         \
    BP_ = w2t + (size_t)E_ * (HID * C_DIM) + (size_t)((N0_ >> 7) * NKB) * 4096 + l8; \
  }

#define STAGE_B(AP_, BP_, TS_, SB_)                                           \
  {                                                                           \
    gll16(AP_ + (TS_) * 4096,        &As[SB_][wbase]);                        \
    gll16(AP_ + (TS_) * 4096 + 2048, &As[SB_][2048 + wbase]);                 \
    gll16(BP_ + (TS_) * 4096,        &Bs[SB_][wbase]);                        \
    gll16(BP_ + (TS_) * 4096 + 2048, &Bs[SB_][2048 + wbase]);                 \
  }

#define STEP_B(T_, RB_, SB_)                                                  \
  {                                                                           \
    if (has_next || (T_) < NKB - 1)                                           \
      asm volatile("s_waitcnt vmcnt(4)" ::: "memory");                        \
    else                                                                      \
      asm volatile("s_waitcnt vmcnt(0)" ::: "memory");                        \
    __builtin_amdgcn_s_barrier();                                             \
    asm volatile("" ::: "memory");                                            \
    const int ts_ = (T_) + 2;                                                 \
    if (ts_ < NKB) {                                                          \
      STAGE_B(aP, bP, ts_, SB_);                                              \
    } else if (has_next) {                                                    \
      STAGE_B(naP, nbP, ts_ - NKB, SB_);                                      \
    }                                                                         \
    s16x8 af[4], bfr[4];                                                      \
    _Pragma("unroll") for (int mf = 0; mf < 4; mf++)                          \
        af[mf] = *(const s16x8*)&As[RB_][(wm * 64 + mf * 16 + lrow) * 32 + fswz]; \
    _Pragma("unroll") for (int nf = 0; nf < 4; nf++)                          \
        bfr[nf] = *(const s16x8*)&Bs[RB_][(wn * 64 + nf * 16 + lrow) * 32 + fswz]; \
    __builtin_amdgcn_s_setprio(1);                                            \
    _Pragma("unroll") for (int mf = 0; mf < 4; mf++)                          \
      _Pragma("unroll") for (int nf = 0; nf < 4; nf++)                        \
        acc[mf][nf] = __builtin_amdgcn_mfma_f32_16x16x32_bf16(af[mf], bfr[nf], acc[mf][nf], 0, 0, 0); \
    __builtin_amdgcn_s_setprio(0);                                            \
  }

  int e, hb, n0;
  const unsigned short *aP, *bP;
  ADDR_B(vt, e, hb, n0, aP, bP);
  STAGE_B(aP, bP, 0, 0);
  STAGE_B(aP, bP, 1, 1);

  while (true) {
    if (tid == 0) vt_s = atomicAdd(q, 1);
    __syncthreads();
    const int vt_next = vt_s;
    const bool has_next = vt_next < total;
    int ne = 0, nhb = 0, nn0 = 0;
    const unsigned short *naP = nullptr, *nbP = nullptr;
    if (has_next) ADDR_B(vt_next, ne, nhb, nn0, naP, nbP);
    f32x4 acc[4][4] = {};
    for (int tt = 0; tt < NKB; tt += 3) {
      STEP_B(tt + 0, 0, 2);
      STEP_B(tt + 1, 1, 0);
      STEP_B(tt + 2, 2, 1);
    }
#pragma unroll
    for (int mf = 0; mf < 4; mf++)
#pragma unroll
      for (int nf = 0; nf < 4; nf++) {
        const int col = n0 + wn * 64 + nf * 16 + lrow;
        const float bb = b2[e * C_DIM + col];
#pragma unroll
        for (int r = 0; r < 4; r++) {
          const int gr = wm * 64 + mf * 16 + lgrp * 4 + r;
          Out[(size_t)(hb + gr) * C_DIM + col] = acc[mf][nf][r] + bb;
        }
      }
    if (!has_next) break;
    vt = vt_next;
    e = ne; hb = nhb; n0 = nn0;
    aP = naP; bP = nbP;
  }
#undef STEP_B
#undef STAGE_B
#undef ADDR_B
}

// combine pairs + transpose to (B, C, HW)
__global__ __launch_bounds__(256) void k_combine(
    const float* __restrict__ Out, const int* __restrict__ offsets,
    const int* __restrict__ counts, const int* __restrict__ pairE,
    const int* __restrict__ pairPos, const float* __restrict__ pairW,
    float* __restrict__ out) {
  __shared__ float tile[32][33];
  const int b = blockIdx.z;
  const int c0 = blockIdx.y * 32;
  const int hw0 = blockIdx.x * 32;
  const int tx = threadIdx.x, ty = threadIdx.y;
#pragma unroll
  for (int i = 0; i < 4; i++) {
    const int n = b * HW + hw0 + ty + i * 8;
    float v = 0.f;
#pragma unroll
    for (int s = 0; s < 2; s++) {
      const int e = pairE[2 * n + s];
      if (e >= 0) {
        const int pos = pairPos[2 * n + s];
        if (pos < counts[e]) {
          const int idx = offsets[e] + pos;
          v += pairW[2 * n + s] * Out[(size_t)idx * C_DIM + c0 + tx];
        }
      }
    }
    tile[ty + i * 8][tx] = v;
  }
  __syncthreads();
#pragma unroll
  for (int i = 0; i < 4; i++) {
    out[((size_t)b * C_DIM + c0 + ty + i * 8) * HW + hw0 + tx] = tile[tx][ty + i * 8];
  }
}

extern "C" void kernel_launch(void* const* d_in, const int* in_sizes, int n_in,
                              void* d_out, int out_size, void* d_ws, size_t ws_size,
                              hipStream_t stream) {
  const float* x = (const float*)d_in[0];
  const float* noise = (const float*)d_in[1];
  const float* wg = (const float*)d_in[2];
  const float* bg = (const float*)d_in[3];
  const float* wn = (const float*)d_in[4];
  const float* bn = (const float*)d_in[5];
  const float* w1 = (const float*)d_in[6];
  const float* b1 = (const float*)d_in[7];
  const float* w2 = (const float*)d_in[8];
  const float* b2 = (const float*)d_in[9];
  const float* w3 = (const float*)d_in[10];
  const float* b3 = (const float*)d_in[11];
  float* out = (float*)d_out;

  char* ws = (char*)d_ws;
  float* Outb = (float*)ws;
  unsigned short* Xbf = (unsigned short*)ws;
  ws += (size_t)MAXROWS * C_DIM * 4;
  unsigned short* Xg = (unsigned short*)ws;  ws += (size_t)MAXROWS * C_DIM * 2;
  unsigned short* w1t = (unsigned short*)ws; ws += (size_t)E_NUM * C_DIM * HID * 2;
  unsigned short* w3t = (unsigned short*)ws; ws += (size_t)E_NUM * C_DIM * HID * 2;
  unsigned short* w2t = (unsigned short*)ws; ws += (size_t)E_NUM * HID * C_DIM * 2;
  unsigned short* H = (unsigned short*)ws;   ws += (size_t)MAXROWS * HID * 2;
  float* partials = (float*)ws;              ws += (size_t)NSL * 16 * N_TOK * 4;
  int* counts = (int*)ws;                    ws += 256;   // [0..7] counts, [8] qA, [9] qB
  int* offsets = (int*)ws;                   ws += 256;
  int* tmap = (int*)ws;                      ws += 256;
  int* tok_list = (int*)ws;                  ws += (size_t)E_NUM * N_TOK * 4;
  int* pairE = (int*)ws;                     ws += (size_t)N_TOK * 2 * 4;
  int* pairPos = (int*)ws;                   ws += (size_t)N_TOK * 2 * 4;
  float* pairW = (float*)ws;                 ws += (size_t)N_TOK * 2 * 4;

  hipMemsetAsync(counts, 0, 64, stream);

  k_gate1<<<dim3((N_TOK / GT) * NSL), dim3(256), 0, stream>>>(x, wg, wn, partials, Xbf);
  k_prep_all<<<dim3(27648), dim3(32, 8), 0, stream>>>(w1, w3, w2, w1t, w3t, w2t);
  k_gate2<<<dim3(N_TOK / 256), dim3(256), 0, stream>>>(partials, bg, bn, noise,
                                                       counts, tok_list, pairE,
                                                       pairPos, pairW);
  k_scan<<<1, 32, 0, stream>>>(counts, offsets, tmap);
  k_compact<<<dim3(1024), dim3(256), 0, stream>>>(Xbf, offsets, counts, tok_list, Xg);
  k_ffn_a<<<dim3(768), dim3(256), 0, stream>>>(Xg, w1t, b1, w3t, b3, offsets, tmap,
                                               counts + 8, H);
  k_ffn_b<<<dim3(768), dim3(256), 0, stream>>>(H, w2t, b2, offsets, tmap,
                                               counts + 9, Outb);
  k_combine<<<dim3(HW / 32, C_DIM / 32, BATCH), dim3(32, 8), 0, stream>>>(
      Outb, offsets, counts, pairE, pairPos, pairW, out);
}

// Round 13
// 296.132 us; speedup vs baseline: 1.1000x; 1.1000x over previous
//
#include <hip/hip_runtime.h>

#define BATCH 8
#define C_DIM 768
#define HW 2304
#define N_TOK 18432   // BATCH*HW
#define E_NUM 8
#define HID 1536

#define BM 128
#define NT_A (HID / 64)          // 24 n-tiles (BN=64, two B matrices)
#define NT_B (C_DIM / 128)       // 6 n-tiles  (BN=128)
#define NKA (C_DIM / 32)         // 24 K-steps pass A (div by 3)
#define NKB (HID / 32)           // 48 K-steps pass B (div by 3)
#define MAXROWS (N_TOK + 1024)   // padded routed-row capacity (152 panels)

#define GT 64                    // gate: tokens per block
#define KSL 256                  // gate: K-slice per block
#define NSL (C_DIM / KSL)        // 3 slices
#define GATE_BLKS ((N_TOK / GT) * NSL)   // 864
#define PREP_BLKS 27648

typedef short s16x8 __attribute__((ext_vector_type(8)));
typedef unsigned short u16x8 __attribute__((ext_vector_type(8)));
typedef float f32x4 __attribute__((ext_vector_type(4)));

__device__ __forceinline__ unsigned short f2bf(float f) {
  unsigned int u = __float_as_uint(f);
  u = u + 0x7fffu + ((u >> 16) & 1u);
  return (unsigned short)(u >> 16);
}

// async global -> LDS, 16B per lane; LDS dest = wave-uniform base + lane*16
__device__ __forceinline__ void gll16(const unsigned short* g, unsigned short* l) {
  __builtin_amdgcn_global_load_lds(
      (const __attribute__((address_space(1))) unsigned int*)g,
      (__attribute__((address_space(3))) unsigned int*)l, 16, 0, 0);
}

// fused gate-stage-1 + weight-prep mega-kernel.
// blocks [0, GATE_BLKS): gating partials + Xbf emission (latency-bound)
// blocks [GATE_BLKS, GATE_BLKS+PREP_BLKS): weight pack fp32->bf16 (BW-bound)
// Independent work: co-residency hides gate latency under prep bandwidth.
__global__ __launch_bounds__(256) void k_gate_prep(
    const float* __restrict__ x, const float* __restrict__ wg,
    const float* __restrict__ wn, float* __restrict__ partials,
    unsigned short* __restrict__ Xbf,
    const float* __restrict__ w1, const float* __restrict__ w3,
    const float* __restrict__ w2, unsigned short* __restrict__ w1t,
    unsigned short* __restrict__ w3t, unsigned short* __restrict__ w2t) {
  __shared__ __align__(16) char smem[33024];
  const int tid = threadIdx.x;

  if (blockIdx.x < GATE_BLKS) {
    // ---- gate1 path ----
    float* Ws = (float*)smem;                       // KSL*16 f = 16384 B
    float(*Xs)[65] = (float(*)[65])(smem + 16384);  // 64*65 f = 16640 B
    const int lane = tid & 63;
    const int og = tid >> 6;
    const int g = blockIdx.x / NSL;
    const int s = blockIdx.x - g * NSL;
    const int n0 = g * GT;
    const int b = n0 / HW;
    const int hw0 = n0 % HW;
    const int k0 = s * KSL;
    const float* xb = x + ((size_t)b * C_DIM + k0) * HW + hw0;

    for (int idx = tid; idx < KSL * 8; idx += 256) {
      const int r = idx >> 3, c = idx & 7;
      Ws[r * 16 + c] = wg[(k0 + r) * 8 + c];
      Ws[r * 16 + 8 + c] = wn[(k0 + r) * 8 + c];
    }

    const int cl = tid >> 2, q = tid & 3;
    const int xr = tid >> 2, xc = (tid & 3) << 4;
    float acc[4] = {};
    float4 xv[4];
#pragma unroll
    for (int i = 0; i < 4; i++)
      xv[i] = *(const float4*)(xb + (size_t)cl * HW + q * 16 + i * 4);

    for (int kc = 0; kc < KSL; kc += GT) {
      __syncthreads();
#pragma unroll
      for (int i = 0; i < 4; i++) {
        const int col = q * 16 + i * 4;
        Xs[cl][col + 0] = xv[i].x;
        Xs[cl][col + 1] = xv[i].y;
        Xs[cl][col + 2] = xv[i].z;
        Xs[cl][col + 3] = xv[i].w;
      }
      __syncthreads();
      if (kc + GT < KSL) {
#pragma unroll
        for (int i = 0; i < 4; i++)
          xv[i] = *(const float4*)(xb + (size_t)(kc + GT + cl) * HW + q * 16 + i * 4);
      }
      {
        u16x8 pa, pb;
#pragma unroll
        for (int j = 0; j < 8; j++) pa[j] = f2bf(Xs[xc + j][xr]);
#pragma unroll
        for (int j = 0; j < 8; j++) pb[j] = f2bf(Xs[xc + 8 + j][xr]);
        *(u16x8*)&Xbf[(size_t)(n0 + xr) * C_DIM + k0 + kc + xc] = pa;
        *(u16x8*)&Xbf[(size_t)(n0 + xr) * C_DIM + k0 + kc + xc + 8] = pb;
      }
#pragma unroll 16
      for (int k = 0; k < GT; k++) {
        const float xk = Xs[k][lane];
        const float4 wv = *(const float4*)&Ws[(kc + k) * 16 + og * 4];
        acc[0] = fmaf(xk, wv.x, acc[0]);
        acc[1] = fmaf(xk, wv.y, acc[1]);
        acc[2] = fmaf(xk, wv.z, acc[2]);
        acc[3] = fmaf(xk, wv.w, acc[3]);
      }
    }
#pragma unroll
    for (int j = 0; j < 4; j++)
      partials[((size_t)s * 16 + og * 4 + j) * N_TOK + n0 + lane] = acc[j];
  } else {
    // ---- prep path ----
    float(*tile)[33] = (float(*)[33])smem;
    int gid = blockIdx.x - GATE_BLKS;
    const float* in;
    unsigned short* outT;
    int S, NK, PSH, bx, by, e;
    if (gid < 9216) {                 // w1: PSH=6 (64-col panels)
      in = w1; outT = w1t; S = HID; NK = NKA; PSH = 6;
      bx = gid % 48; by = (gid / 48) % 24; e = gid / (48 * 24);
    } else if (gid < 18432) {         // w3
      gid -= 9216;
      in = w3; outT = w3t; S = HID; NK = NKA; PSH = 6;
      bx = gid % 48; by = (gid / 48) % 24; e = gid / (48 * 24);
    } else {                          // w2: PSH=7 (128-col panels)
      gid -= 18432;
      in = w2; outT = w2t; S = C_DIM; NK = NKB; PSH = 7;
      bx = gid % 24; by = (gid / 24) % 48; e = gid / (24 * 48);
    }
    const int s0 = bx * 32, r0 = by * 32;
    const int tx = tid & 31, ty = tid >> 5;
    const size_t esz = (size_t)C_DIM * HID;
    const float* ip = in + (size_t)e * esz;
    unsigned short* op = outT + (size_t)e * esz;
#pragma unroll
    for (int i = 0; i < 4; i++) {
      tile[ty + i * 8][tx] = ip[(size_t)(r0 + ty + i * 8) * S + s0 + tx];
    }
    __syncthreads();
    const int t = r0 >> 5;
    const int q = tx >> 3;
#pragma unroll
    for (int i = 0; i < 4; i++) {
      const int s = s0 + ty + i * 8;
      const int nloc = s & ((1 << PSH) - 1);
      const int pn = s >> PSH;
      const int slot = q ^ ((nloc >> 1) & 3);
      op[(size_t)(pn * NK + t) * (32 << PSH) + nloc * 32 + (slot << 3) + (tx & 7)] =
          f2bf(tile[tx][ty + i * 8]);
    }
  }
}

// gate stage 2: 1 thread per token; fixed-order slice sum -> exact epilogue
__global__ __launch_bounds__(256) void k_gate2(const float* __restrict__ partials,
                                               const float* __restrict__ bg,
                                               const float* __restrict__ bn,
                                               const float* __restrict__ noise,
                                               int* __restrict__ counts,
                                               int* __restrict__ tok_list,
                                               int* __restrict__ pairE,
                                               int* __restrict__ pairPos,
                                               float* __restrict__ pairW) {
  const int n = blockIdx.x * 256 + threadIdx.x;
  if (n >= N_TOK) return;
  float v[16];
#pragma unroll
  for (int e = 0; e < 16; e++) {
    const float p0 = partials[(size_t)(0 * 16 + e) * N_TOK + n];
    const float p1 = partials[(size_t)(1 * 16 + e) * N_TOK + n];
    const float p2 = partials[(size_t)(2 * 16 + e) * N_TOK + n];
    v[e] = (p0 + p1) + p2;
  }
  const float4 nz0 = *(const float4*)(noise + (size_t)n * 8);
  const float4 nz1 = *(const float4*)(noise + (size_t)n * 8 + 4);
  const float nzv[8] = {nz0.x, nz0.y, nz0.z, nz0.w, nz1.x, nz1.y, nz1.z, nz1.w};
  float noisy[E_NUM];
#pragma unroll
  for (int e = 0; e < E_NUM; e++) {
    const float lg = v[e] + bg[e];
    const float nl = v[8 + e] + bn[e];
    const float sp = (nl > 20.f) ? nl : log1pf(expf(nl));
    noisy[e] = lg + nzv[e] * sp;
  }
  int i0 = 0;
#pragma unroll
  for (int e = 1; e < E_NUM; e++) if (noisy[e] > noisy[i0]) i0 = e;
  int i1 = (i0 == 0) ? 1 : 0;
#pragma unroll
  for (int e = 0; e < E_NUM; e++) if (e != i0 && noisy[e] > noisy[i1]) i1 = e;
  const float v0 = noisy[i0], v1 = noisy[i1];
  const float e1 = expf(v1 - v0);
  const float z = 1.f + e1;
  const float p0 = (i0 == 0) ? (1.f / z) : ((i1 == 0) ? (e1 / z) : 0.f);
  const float p1 = (i0 == 1) ? (1.f / z) : ((i1 == 1) ? (e1 / z) : 0.f);
  if (p0 != 0.f) {
    const int pos = atomicAdd(&counts[i0], 1);
    tok_list[i0 * N_TOK + pos] = n;
    pairE[2 * n] = i0; pairPos[2 * n] = pos; pairW[2 * n] = p0;
  } else {
    pairE[2 * n] = -1;
  }
  if (p1 != 0.f) {
    const int pos = atomicAdd(&counts[i1], 1);
    tok_list[i1 * N_TOK + pos] = n;
    pairE[2 * n + 1] = i1; pairPos[2 * n + 1] = pos; pairW[2 * n + 1] = p1;
  } else {
    pairE[2 * n + 1] = -1;
  }
}

// scan: 128-aligned per-expert offsets + active-tile prefix tables
__global__ void k_scan(int* __restrict__ counts, int* __restrict__ offsets,
                       int* __restrict__ tmap) {
  if (threadIdx.x == 0) {
    int s = 0, ta = 0, tb = 0;
    for (int e = 0; e < E_NUM; e++) {
      offsets[e] = s;
      int c = counts[e];
      if (c > N_TOK - s) c = (N_TOK - s > 0) ? (N_TOK - s) : 0;
      counts[e] = c;
      tmap[e] = ta; tmap[16 + e] = tb;
      const int mt = (c + BM - 1) / BM;
      s += mt * BM;
      ta += mt * NT_A;
      tb += mt * NT_B;
    }
    offsets[E_NUM] = s;
    tmap[8] = ta; tmap[24] = tb;
  }
}

// gather routed rows into packed A-panels: [panel][k-step][128 x 32k, chunk-XOR]
__global__ __launch_bounds__(256) void k_compact(const unsigned short* __restrict__ Xbf,
                                                 const int* __restrict__ offsets,
                                                 const int* __restrict__ counts,
                                                 const int* __restrict__ tok_list,
                                                 unsigned short* __restrict__ Xg) {
  const int total = offsets[E_NUM];
  const int half = threadIdx.x >> 7;
  const int lane = threadIdx.x & 127;
  for (int r = blockIdx.x * 2 + half; r < total; r += gridDim.x * 2) {
    int e = 0;
#pragma unroll
    for (int i = 1; i < E_NUM; i++) if (r >= offsets[i]) e = i;
    int pos = r - offsets[e];
    if (pos >= counts[e]) pos = counts[e] - 1;
    const int tok = tok_list[e * N_TOK + pos];
    if (lane < 96) {
      const int t = lane >> 2, q = lane & 3;
      const uint4 v = ((const uint4*)(Xbf + (size_t)tok * C_DIM))[lane];
      const int r7 = r & 127;
      const int slot = q ^ ((r7 >> 1) & 3);
      *(uint4*)(Xg + (size_t)((r >> 7) * NKA + t) * 4096 + r7 * 32 + (slot << 3)) = v;
    }
  }
}

// pass A: H = silu(Xg@w1+b1) * (Xg@w3+b3); packed panels, persistent linear,
// 3-buffer counted-vmcnt pipeline continuous across tiles; H written packed.
__global__ __launch_bounds__(256, 3) void k_ffn_a(
    const unsigned short* __restrict__ Xg, const unsigned short* __restrict__ w1t,
    const float* __restrict__ b1, const unsigned short* __restrict__ w3t,
    const float* __restrict__ b3, const int* __restrict__ offsets,
    const int* __restrict__ tmap, unsigned short* __restrict__ H) {
  __shared__ __align__(16) unsigned short As[3][BM * 32];   // 24 KB
  __shared__ __align__(16) unsigned short B1s[3][64 * 32];  // 12 KB
  __shared__ __align__(16) unsigned short B3s[3][64 * 32];  // 12 KB
  const int tid = threadIdx.x;
  const int lane = tid & 63;
  const int w = tid >> 6;
  const int wm = w >> 1, wn = w & 1;
  const int lrow = lane & 15, lgrp = lane >> 4;
  const int fswz = (lgrp ^ ((lrow >> 1) & 3)) << 3;
  const int wbase = w << 9;
  const int l8 = tid << 3;   // per-lane 16B offset (shorts)
  const int total = tmap[8];
  int vt = blockIdx.x;
  if (vt >= total) return;

#define ADDR_A(VT_, E_, HB_, N0_, AP_, P1_, P3_)                              \
  {                                                                           \
    E_ = 0;                                                                   \
    _Pragma("unroll") for (int i_ = 1; i_ < E_NUM; i_++)                      \
        if ((VT_) >= tmap[i_]) E_ = i_;                                       \
    const int local_ = (VT_) - tmap[E_];                                      \
    const int tm_ = local_ / NT_A;                                            \
    N0_ = (local_ - tm_ * NT_A) * 64;                                         \
    HB_ = offsets[E_] + tm_ * BM;                                             \
    AP_ = Xg + (size_t)(HB_ >> 7) * (NKA * 4096) + l8;                        \
    P1_ = w1t + (size_t)E_ * (C_DIM * HID) + (size_t)((N0_ >> 6) * NKA) * 2048 + l8; \
    P3_ = w3t + (size_t)E_ * (C_DIM * HID) + (size_t)((N0_ >> 6) * NKA) * 2048 + l8; \
  }

#define STAGE_A(AP_, P1_, P3_, TS_, SB_)                                      \
  {                                                                           \
    gll16(AP_ + (TS_) * 4096,        &As[SB_][wbase]);                        \
    gll16(AP_ + (TS_) * 4096 + 2048, &As[SB_][2048 + wbase]);                 \
    gll16(P1_ + (TS_) * 2048, &B1s[SB_][wbase]);                              \
    gll16(P3_ + (TS_) * 2048, &B3s[SB_][wbase]);                              \
  }

#define STEP_A(T_, RB_, SB_)                                                  \
  {                                                                           \
    if (has_next || (T_) < NKA - 1)                                           \
      asm volatile("s_waitcnt vmcnt(4)" ::: "memory");                        \
    else                                                                      \
      asm volatile("s_waitcnt vmcnt(0)" ::: "memory");                        \
    __builtin_amdgcn_s_barrier();                                             \
    asm volatile("" ::: "memory");                                            \
    const int ts_ = (T_) + 2;                                                 \
    if (ts_ < NKA) {                                                          \
      STAGE_A(aP, p1P, p3P, ts_, SB_);                                        \
    } else if (has_next) {                                                    \
      STAGE_A(naP, np1P, np3P, ts_ - NKA, SB_);                               \
    }                                                                         \
    s16x8 af[4], bf1[2], bf3[2];                                              \
    _Pragma("unroll") for (int mf = 0; mf < 4; mf++)                          \
        af[mf] = *(const s16x8*)&As[RB_][(wm * 64 + mf * 16 + lrow) * 32 + fswz]; \
    _Pragma("unroll") for (int nf = 0; nf < 2; nf++) {                        \
      bf1[nf] = *(const s16x8*)&B1s[RB_][(wn * 32 + nf * 16 + lrow) * 32 + fswz]; \
      bf3[nf] = *(const s16x8*)&B3s[RB_][(wn * 32 + nf * 16 + lrow) * 32 + fswz]; \
    }                                                                         \
    __builtin_amdgcn_s_setprio(1);                                            \
    _Pragma("unroll") for (int mf = 0; mf < 4; mf++)                          \
      _Pragma("unroll") for (int nf = 0; nf < 2; nf++) {                      \
        acc1[mf][nf] = __builtin_amdgcn_mfma_f32_16x16x32_bf16(af[mf], bf1[nf], acc1[mf][nf], 0, 0, 0); \
        acc3[mf][nf] = __builtin_amdgcn_mfma_f32_16x16x32_bf16(af[mf], bf3[nf], acc3[mf][nf], 0, 0, 0); \
      }                                                                       \
    __builtin_amdgcn_s_setprio(0);                                            \
  }

  int e, hb, n0;
  const unsigned short *aP, *p1P, *p3P;
  ADDR_A(vt, e, hb, n0, aP, p1P, p3P);
  STAGE_A(aP, p1P, p3P, 0, 0);
  STAGE_A(aP, p1P, p3P, 1, 1);

  while (true) {
    const int vt_next = vt + (int)gridDim.x;
    const bool has_next = vt_next < total;
    int ne = 0, nhb = 0, nn0 = 0;
    const unsigned short *naP = nullptr, *np1P = nullptr, *np3P = nullptr;
    if (has_next) ADDR_A(vt_next, ne, nhb, nn0, naP, np1P, np3P);
    f32x4 acc1[4][2] = {};
    f32x4 acc3[4][2] = {};
    for (int tt = 0; tt < NKA; tt += 3) {
      STEP_A(tt + 0, 0, 2);
      STEP_A(tt + 1, 1, 0);
      STEP_A(tt + 2, 2, 1);
    }
    const int Ph = hb >> 7;
#pragma unroll
    for (int mf = 0; mf < 4; mf++)
#pragma unroll
      for (int nf = 0; nf < 2; nf++) {
        const int col = n0 + wn * 32 + nf * 16 + lrow;
        const float bb1 = b1[e * HID + col];
        const float bb3 = b3[e * HID + col];
        const int th = col >> 5;
        const int kq = (col & 31) >> 3;
        const int ko = col & 7;
        unsigned short* hp = H + (size_t)(Ph * NKB + th) * 4096 + ko;
#pragma unroll
        for (int r = 0; r < 4; r++) {
          const int gr = wm * 64 + mf * 16 + lgrp * 4 + r;
          const float g1 = acc1[mf][nf][r] + bb1;
          const float g3 = acc3[mf][nf][r] + bb3;
          const float hv = g1 / (1.f + expf(-g1)) * g3;
          hp[gr * 32 + ((kq ^ ((gr >> 1) & 3)) << 3)] = f2bf(hv);
        }
      }
    if (!has_next) break;
    vt = vt_next;
    e = ne; hb = nhb; n0 = nn0;
    aP = naP; p1P = np1P; p3P = np3P;
  }
#undef STEP_A
#undef STAGE_A
#undef ADDR_A
}

// pass B: Out = H @ w2 + b2; BM=128 x BN=128, packed panels, same pipeline
__global__ __launch_bounds__(256, 3) void k_ffn_b(
    const unsigned short* __restrict__ H, const unsigned short* __restrict__ w2t,
    const float* __restrict__ b2, const int* __restrict__ offsets,
    const int* __restrict__ tmap, float* __restrict__ Out) {
  __shared__ __align__(16) unsigned short As[3][BM * 32];   // 24 KB
  __shared__ __align__(16) unsigned short Bs[3][128 * 32];  // 24 KB
  const int tid = threadIdx.x;
  const int lane = tid & 63;
  const int w = tid >> 6;
  const int wm = w >> 1, wn = w & 1;
  const int lrow = lane & 15, lgrp = lane >> 4;
  const int fswz = (lgrp ^ ((lrow >> 1) & 3)) << 3;
  const int wbase = w << 9;
  const int l8 = tid << 3;
  const int total = tmap[24];
  int vt = blockIdx.x;
  if (vt >= total) return;

#define ADDR_B(VT_, E_, HB_, N0_, AP_, BP_)                                   \
  {                                                                           \
    E_ = 0;                                                                   \
    _Pragma("unroll") for (int i_ = 1; i_ < E_NUM; i_++)                      \
        if ((VT_) >= tmap[16 + i_]) E_ = i_;                                  \
    const int local_ = (VT_) - tmap[16 + E_];                                 \
    const int tm_ = local_ / NT_B;                                            \
    N0_ = (local_ - tm_ * NT_B) * 128;                                        \
    HB_ = offsets[E_] + tm_ * BM;                                             \
    AP_ = H + (size_t)(HB_ >> 7) * (NKB * 4096) + l8;                         \
    BP_ = w2t + (size_t)E_ * (HID * C_DIM) + (size_t)((N0_ >> 7) * NKB) * 4096 + l8; \
  }

#define STAGE_B(AP_, BP_, TS_, SB_)                                           \
  {                                                                           \
    gll16(AP_ + (TS_) * 4096,        &As[SB_][wbase]);                        \
    gll16(AP_ + (TS_) * 4096 + 2048, &As[SB_][2048 + wbase]);                 \
    gll16(BP_ + (TS_) * 4096,        &Bs[SB_][wbase]);                        \
    gll16(BP_ + (TS_) * 4096 + 2048, &Bs[SB_][2048 + wbase]);                 \
  }

#define STEP_B(T_, RB_, SB_)                                                  \
  {                                                                           \
    if (has_next || (T_) < NKB - 1)                                           \
      asm volatile("s_waitcnt vmcnt(4)" ::: "memory");                        \
    else                                                                      \
      asm volatile("s_waitcnt vmcnt(0)" ::: "memory");                        \
    __builtin_amdgcn_s_barrier();                                             \
    asm volatile("" ::: "memory");                                            \
    const int ts_ = (T_) + 2;                                                 \
    if (ts_ < NKB) {                                                          \
      STAGE_B(aP, bP, ts_, SB_);                                              \
    } else if (has_next) {                                                    \
      STAGE_B(naP, nbP, ts_ - NKB, SB_);                                      \
    }                                                                         \
    s16x8 af[4], bfr[4];                                                      \
    _Pragma("unroll") for (int mf = 0; mf < 4; mf++)                          \
        af[mf] = *(const s16x8*)&As[RB_][(wm * 64 + mf * 16 + lrow) * 32 + fswz]; \
    _Pragma("unroll") for (int nf = 0; nf < 4; nf++)                          \
        bfr[nf] = *(const s16x8*)&Bs[RB_][(wn * 64 + nf * 16 + lrow) * 32 + fswz]; \
    __builtin_amdgcn_s_setprio(1);                                            \
    _Pragma("unroll") for (int mf = 0; mf < 4; mf++)                          \
      _Pragma("unroll") for (int nf = 0; nf < 4; nf++)                        \
        acc[mf][nf] = __builtin_amdgcn_mfma_f32_16x16x32_bf16(af[mf], bfr[nf], acc[mf][nf], 0, 0, 0); \
    __builtin_amdgcn_s_setprio(0);                                            \
  }

  int e, hb, n0;
  const unsigned short *aP, *bP;
  ADDR_B(vt, e, hb, n0, aP, bP);
  STAGE_B(aP, bP, 0, 0);
  STAGE_B(aP, bP, 1, 1);

  while (true) {
    const int vt_next = vt + (int)gridDim.x;
    const bool has_next = vt_next < total;
    int ne = 0, nhb = 0, nn0 = 0;
    const unsigned short *naP = nullptr, *nbP = nullptr;
    if (has_next) ADDR_B(vt_next, ne, nhb, nn0, naP, nbP);
    f32x4 acc[4][4] = {};
    for (int tt = 0; tt < NKB; tt += 3) {
      STEP_B(tt + 0, 0, 2);
      STEP_B(tt + 1, 1, 0);
      STEP_B(tt + 2, 2, 1);
    }
#pragma unroll
    for (int mf = 0; mf < 4; mf++)
#pragma unroll
      for (int nf = 0; nf < 4; nf++) {
        const int col = n0 + wn * 64 + nf * 16 + lrow;
        const float bb = b2[e * C_DIM + col];
#pragma unroll
        for (int r = 0; r < 4; r++) {
          const int gr = wm * 64 + mf * 16 + lgrp * 4 + r;
          Out[(size_t)(hb + gr) * C_DIM + col] = acc[mf][nf][r] + bb;
        }
      }
    if (!has_next) break;
    vt = vt_next;
    e = ne; hb = nhb; n0 = nn0;
    aP = naP; bP = nbP;
  }
#undef STEP_B
#undef STAGE_B
#undef ADDR_B
}

// combine pairs + transpose to (B, C, HW)
__global__ __launch_bounds__(256) void k_combine(
    const float* __restrict__ Out, const int* __restrict__ offsets,
    const int* __restrict__ counts, const int* __restrict__ pairE,
    const int* __restrict__ pairPos, const float* __restrict__ pairW,
    float* __restrict__ out) {
  __shared__ float tile[32][33];
  const int b = blockIdx.z;
  const int c0 = blockIdx.y * 32;
  const int hw0 = blockIdx.x * 32;
  const int tx = threadIdx.x, ty = threadIdx.y;
#pragma unroll
  for (int i = 0; i < 4; i++) {
    const int n = b * HW + hw0 + ty + i * 8;
    float v = 0.f;
#pragma unroll
    for (int s = 0; s < 2; s++) {
      const int e = pairE[2 * n + s];
      if (e >= 0) {
        const int pos = pairPos[2 * n + s];
        if (pos < counts[e]) {
          const int idx = offsets[e] + pos;
          v += pairW[2 * n + s] * Out[(size_t)idx * C_DIM + c0 + tx];
        }
      }
    }
    tile[ty + i * 8][tx] = v;
  }
  __syncthreads();
#pragma unroll
  for (int i = 0; i < 4; i++) {
    out[((size_t)b * C_DIM + c0 + ty + i * 8) * HW + hw0 + tx] = tile[tx][ty + i * 8];
  }
}

extern "C" void kernel_launch(void* const* d_in, const int* in_sizes, int n_in,
                              void* d_out, int out_size, void* d_ws, size_t ws_size,
                              hipStream_t stream) {
  const float* x = (const float*)d_in[0];
  const float* noise = (const float*)d_in[1];
  const float* wg = (const float*)d_in[2];
  const float* bg = (const float*)d_in[3];
  const float* wn = (const float*)d_in[4];
  const float* bn = (const float*)d_in[5];
  const float* w1 = (const float*)d_in[6];
  const float* b1 = (const float*)d_in[7];
  const float* w2 = (const float*)d_in[8];
  const float* b2 = (const float*)d_in[9];
  const float* w3 = (const float*)d_in[10];
  const float* b3 = (const float*)d_in[11];
  float* out = (float*)d_out;

  char* ws = (char*)d_ws;
  // region0: Xbf (bf16, written by gate path, read by compact) aliases front of
  // Outb (fp32, written by ffn_b AFTER compact in stream order).
  float* Outb = (float*)ws;
  unsigned short* Xbf = (unsigned short*)ws;
  ws += (size_t)MAXROWS * C_DIM * 4;
  unsigned short* Xg = (unsigned short*)ws;  ws += (size_t)MAXROWS * C_DIM * 2;
  unsigned short* w1t = (unsigned short*)ws; ws += (size_t)E_NUM * C_DIM * HID * 2;
  unsigned short* w3t = (unsigned short*)ws; ws += (size_t)E_NUM * C_DIM * HID * 2;
  unsigned short* w2t = (unsigned short*)ws; ws += (size_t)E_NUM * HID * C_DIM * 2;
  unsigned short* H = (unsigned short*)ws;   ws += (size_t)MAXROWS * HID * 2;
  float* partials = (float*)ws;              ws += (size_t)NSL * 16 * N_TOK * 4;
  int* counts = (int*)ws;                    ws += 256;
  int* offsets = (int*)ws;                   ws += 256;
  int* tmap = (int*)ws;                      ws += 256;
  int* tok_list = (int*)ws;                  ws += (size_t)E_NUM * N_TOK * 4;
  int* pairE = (int*)ws;                     ws += (size_t)N_TOK * 2 * 4;
  int* pairPos = (int*)ws;                   ws += (size_t)N_TOK * 2 * 4;
  float* pairW = (float*)ws;                 ws += (size_t)N_TOK * 2 * 4;

  hipMemsetAsync(counts, 0, 64, stream);

  k_gate_prep<<<dim3(GATE_BLKS + PREP_BLKS), dim3(256), 0, stream>>>(
      x, wg, wn, partials, Xbf, w1, w3, w2, w1t, w3t, w2t);
  k_gate2<<<dim3(N_TOK / 256), dim3(256), 0, stream>>>(partials, bg, bn, noise,
                                                       counts, tok_list, pairE,
                                                       pairPos, pairW);
  k_scan<<<1, 32, 0, stream>>>(counts, offsets, tmap);
  k_compact<<<dim3(1024), dim3(256), 0, stream>>>(Xbf, offsets, counts, tok_list, Xg);
  k_ffn_a<<<dim3(768), dim3(256), 0, stream>>>(Xg, w1t, b1, w3t, b3, offsets, tmap, H);
  k_ffn_b<<<dim3(768), dim3(256), 0, stream>>>(H, w2t, b2, offsets, tmap, Outb);
  k_combine<<<dim3(HW / 32, C_DIM / 32, BATCH), dim3(32, 8), 0, stream>>>(
      Outb, offsets, counts, pairE, pairPos, pairW, out);
}